// Round 1
// baseline (791.969 us; speedup 1.0000x reference)
//
#include <hip/hip_runtime.h>
#include <stdint.h>

#define B_ 32
#define S_ 512
#define I_ 256
#define H_ 512
#define OUTW 1024
#define OUTS_ELEMS (B_*S_*OUTW)   // 16777216

typedef _Float16 f16;
typedef _Float16 half2_t __attribute__((ext_vector_type(2)));

__device__ __forceinline__ float fdot2(uint32_t a, uint32_t b, float c){
#if __has_builtin(__builtin_amdgcn_fdot2)
  return __builtin_amdgcn_fdot2(__builtin_bit_cast(half2_t, a),
                                __builtin_bit_cast(half2_t, b), c, false);
#else
  half2_t ha = __builtin_bit_cast(half2_t, a);
  half2_t hb = __builtin_bit_cast(half2_t, b);
  return c + (float)ha.x*(float)hb.x + (float)ha.y*(float)hb.y;
#endif
}

__device__ __forceinline__ uint32_t packf16(float x, float y){
  union { f16 h[2]; uint32_t u; } z;
  z.h[0] = (f16)x; z.h[1] = (f16)y;
  return z.u;
}

template<int CTRL>
__device__ __forceinline__ float dpp_xor_add(float x){
  int v = __builtin_amdgcn_update_dpp(0, __float_as_int(x), CTRL, 0xF, 0xF, true);
  return x + __int_as_float(v);
}

// ---------------------------------------------------------------------------
// P0: convert W_hh (both dirs) fp32 -> f16 into d_ws:  wf16[2][512][512]
// ---------------------------------------------------------------------------
__global__ __launch_bounds__(256) void cvt_w_kernel(const float* __restrict__ wf,
                                                    const float* __restrict__ wb,
                                                    f16* __restrict__ out){
  int i = blockIdx.x*256 + threadIdx.x;        // 0..65535, 8 elems each
  const float* src = (i < 32768) ? wf : wb;
  int base = (i & 32767) * 8;
  float4 a = *(const float4*)(src + base);
  float4 c = *(const float4*)(src + base + 4);
  uint4 o;
  o.x = packf16(a.x, a.y); o.y = packf16(a.z, a.w);
  o.z = packf16(c.x, c.y); o.w = packf16(c.z, c.w);
  *(uint4*)(out + (size_t)i*8) = o;
}

// ---------------------------------------------------------------------------
// P1: xp[t][b][j] = sum_i x[b][t][i]*W_ih[dir][j][i] + b_ih[j]+b_hh[j]
// written into d_out outputs area at [b][t][j_global]  (staging; recurrent
// kernel reads each cell exactly once before overwriting it with h).
// Tiled fp32 GEMM: M-tile 128 (rows r = t*32+b), N-tile 64 (j), K-tile 32.
// ---------------------------------------------------------------------------
#define PTM 128
#define PTN 64
#define PTK 32
__global__ __launch_bounds__(256) void proj_kernel(
    const float* __restrict__ x,
    const float* __restrict__ wihf, const float* __restrict__ wihb,
    const float* __restrict__ bihf, const float* __restrict__ bhhf,
    const float* __restrict__ bihb, const float* __restrict__ bhhb,
    float* __restrict__ out)
{
  __shared__ float As[PTK][132];   // transposed [k][r], stride 132 (16B-aligned, conflict-light)
  __shared__ float Bs[PTK][68];    // transposed [k][j]
  const int tid = threadIdx.x;
  const int row0 = blockIdx.x * PTM;
  const int j0   = blockIdx.y * PTN;
  const int dir  = (j0 >= 512) ? 1 : 0;
  const int jl0  = j0 - dir*512;
  const float* wih = dir ? wihb : wihf;
  const float* bi  = dir ? bihb : bihf;
  const float* bh  = dir ? bhhb : bhhf;

  const int ty = tid >> 4, tx = tid & 15;   // 16x16 threads; micro-tile 8x4
  float acc[8][4];
#pragma unroll
  for (int i=0;i<8;i++)
#pragma unroll
    for (int j=0;j<4;j++) acc[i][j] = 0.f;

  float bias[4];
#pragma unroll
  for (int jj=0;jj<4;jj++){ int jl = jl0 + tx*4 + jj; bias[jj] = bi[jl] + bh[jl]; }

  for (int k0 = 0; k0 < I_; k0 += PTK){
    { // A: 128 rows x 32 k
      int r = tid >> 1, kh = (tid & 1) * 16;
      int rg = row0 + r; int bb = rg & 31, tt = rg >> 5;
      const float* ap = x + ((size_t)bb*S_ + tt)*I_ + k0 + kh;
#pragma unroll
      for (int u=0;u<4;u++){
        float4 v = *(const float4*)(ap + u*4);
        As[kh+u*4+0][r] = v.x; As[kh+u*4+1][r] = v.y;
        As[kh+u*4+2][r] = v.z; As[kh+u*4+3][r] = v.w;
      }
    }
    { // B: 64 j x 32 k
      int jr = tid >> 2, kh = (tid & 3) * 8;
      const float* bp = wih + (size_t)(jl0 + jr)*I_ + k0 + kh;
#pragma unroll
      for (int u=0;u<2;u++){
        float4 v = *(const float4*)(bp + u*4);
        Bs[kh+u*4+0][jr] = v.x; Bs[kh+u*4+1][jr] = v.y;
        Bs[kh+u*4+2][jr] = v.z; Bs[kh+u*4+3][jr] = v.w;
      }
    }
    __syncthreads();
#pragma unroll 8
    for (int kk=0; kk<PTK; ++kk){
      const float4 a0 = *(const float4*)&As[kk][ty*8+0];
      const float4 a1 = *(const float4*)&As[kk][ty*8+4];
      const float4 bq = *(const float4*)&Bs[kk][tx*4];
      const float av[8] = {a0.x,a0.y,a0.z,a0.w,a1.x,a1.y,a1.z,a1.w};
      const float bv[4] = {bq.x,bq.y,bq.z,bq.w};
#pragma unroll
      for (int i=0;i<8;i++)
#pragma unroll
        for (int j=0;j<4;j++) acc[i][j] = fmaf(av[i], bv[j], acc[i][j]);
    }
    __syncthreads();
  }
#pragma unroll
  for (int i=0;i<8;i++){
    int rg = row0 + ty*8 + i; int bb = rg & 31, tt = rg >> 5;
    float* op = out + ((size_t)bb*S_ + tt)*OUTW + j0 + tx*4;
    float4 v = {acc[i][0]+bias[0], acc[i][1]+bias[1], acc[i][2]+bias[2], acc[i][3]+bias[3]};
    *(float4*)op = v;
  }
}

// ---------------------------------------------------------------------------
// R: persistent recurrence. 64 WGs = (dir, batch). 512 thr = 8 waves.
// Lane l: jg = l>>3 (0..63), ks = l&7 (k-slice of 64).
// Rows j = jg + 64*m: m=0..5 -> W in VGPRs (192 regs packed f16);
//                     m=6,7 (rows 384..511) -> W in LDS (128KB, XOR-swizzled).
// h (f16, 1KB) double-buffered in LDS (ks-XOR-swizzled layout).
// k-reduce over 8 ks-lanes: DPP xor1 + DPP xor2 + one shfl_xor(4).
// Lane finalizes row j = jg + 64*ks; writes output (overwriting its xp slot).
// ---------------------------------------------------------------------------
#define LDSW 131072          // 128 rows * 1KB
#define LDS_TOTAL (LDSW + 2048)

#define ROWR(ACC, R) \
  ACC = fdot2(wreg[R][c*4+0], hv.x, ACC); \
  ACC = fdot2(wreg[R][c*4+1], hv.y, ACC); \
  ACC = fdot2(wreg[R][c*4+2], hv.z, ACC); \
  ACC = fdot2(wreg[R][c*4+3], hv.w, ACC);

#define ROWL(ACC, WV) \
  ACC = fdot2(WV.x, hv.x, ACC); ACC = fdot2(WV.y, hv.y, ACC); \
  ACC = fdot2(WV.z, hv.z, ACC); ACC = fdot2(WV.w, hv.w, ACC);

__global__ __launch_bounds__(512, 2) void rnn_kernel(
    const f16* __restrict__ Wall,   // [2][512][512] f16
    const float* __restrict__ h0,   // [2][32][512]
    float* dout)
{
  extern __shared__ char lds[];
  const int tid = threadIdx.x;
  const int dir = blockIdx.x >> 5;
  const int b   = blockIdx.x & 31;
  const int jg  = tid >> 3;
  const int ks  = tid & 7;
  const f16* W = Wall + (size_t)dir * (H_*(size_t)H_);
  float* outs = dout + (size_t)b * (S_*OUTW) + dir * H_;       // (t,j): outs[t*1024+j]
  float* hn   = dout + (size_t)OUTS_ELEMS + ((size_t)dir*B_ + b) * H_;

  // ---- W rows m=0..5 into registers (packed f16 pairs)
  uint32_t wreg[6][32];
#pragma unroll
  for (int m=0;m<6;m++){
    const uint4* src = (const uint4*)(W + ((size_t)(jg + 64*m))*H_ + ks*64);
#pragma unroll
    for (int c=0;c<8;c++){
      uint4 v = src[c];
      wreg[m][c*4+0]=v.x; wreg[m][c*4+1]=v.y;
      wreg[m][c*4+2]=v.z; wreg[m][c*4+3]=v.w;
    }
  }
  // ---- W rows 384..511 into LDS, swizzled: chunk (r, c=ks*8+i) stored at
  //      r*1024 + ks*128 + (i ^ ((ks^r)&7))*16  -> balanced banks on reads
  {
    int r = tid >> 2, q = tid & 3;
    const uint4* src = (const uint4*)(W + ((size_t)(384 + r))*H_);
#pragma unroll
    for (int cc=0;cc<16;cc++){
      int c = q*16 + cc;
      int kss = c >> 3;
      int ii2 = (c & 7) ^ ((kss ^ r) & 7);
      *((uint4*)(lds + r*1024 + kss*128 + ii2*16)) = src[c];
    }
  }
  // ---- h0 -> hbuf[0] (swizzled: j at  (j>>6)*128 + (((j>>3)&7)^(j>>6))&7)*16 + (j&7)*2 )
  {
    int j = tid;
    int off = (j>>6)*128 + ((((j>>3)&7) ^ (j>>6)) & 7)*16 + (j&7)*2;
    *((f16*)(lds + LDSW + off)) = (f16)h0[((size_t)dir*B_ + b)*H_ + j];
  }
  __syncthreads();

  const int jfin = jg + 64*ks;
  const int sw16 = ((ks ^ jg) & 7) << 4;
  const int w6o = jg*1024 + ks*128 + sw16;          // phys = w6o ^ (c<<4)
  const int w7o = (64+jg)*1024 + ks*128 + sw16;
  const int hxo = ks*128 + (ks<<4);                 // phys = hxo ^ (c<<4)
  const int hwoff = (jfin>>6)*128 + ((((jfin>>3)&7) ^ (jfin>>6)) & 7)*16 + (jfin&7)*2;

  float h_last = 0.f;
  int cur = 0;
  for (int s=0; s<S_; ++s){
    const int t = dir ? (S_-1-s) : s;
    float* xo = outs + (size_t)t*OUTW;
    float xpv = xo[jfin];                           // read xp before overwrite
    float acc0=0.f,acc1=0.f,acc2=0.f,acc3=0.f,acc4=0.f,acc5=0.f,acc6=0.f,acc7=0.f;
    const char* hbase = lds + LDSW + (cur<<10);
#pragma unroll
    for (int c=0;c<8;c++){
      const uint4 hv = *(const uint4*)(hbase + (hxo ^ (c<<4)));
      const uint4 w6 = *(const uint4*)(lds + (w6o ^ (c<<4)));
      const uint4 w7 = *(const uint4*)(lds + (w7o ^ (c<<4)));
      ROWR(acc0, 0) ROWR(acc1, 1) ROWR(acc2, 2)
      ROWR(acc3, 3) ROWR(acc4, 4) ROWR(acc5, 5)
      ROWL(acc6, w6) ROWL(acc7, w7)
    }
    // reduce over the 8 ks-lanes (same jg): xor1, xor2 via DPP quad_perm
    acc0 = dpp_xor_add<0xB1>(acc0); acc1 = dpp_xor_add<0xB1>(acc1);
    acc2 = dpp_xor_add<0xB1>(acc2); acc3 = dpp_xor_add<0xB1>(acc3);
    acc4 = dpp_xor_add<0xB1>(acc4); acc5 = dpp_xor_add<0xB1>(acc5);
    acc6 = dpp_xor_add<0xB1>(acc6); acc7 = dpp_xor_add<0xB1>(acc7);
    acc0 = dpp_xor_add<0x4E>(acc0); acc1 = dpp_xor_add<0x4E>(acc1);
    acc2 = dpp_xor_add<0x4E>(acc2); acc3 = dpp_xor_add<0x4E>(acc3);
    acc4 = dpp_xor_add<0x4E>(acc4); acc5 = dpp_xor_add<0x4E>(acc5);
    acc6 = dpp_xor_add<0x4E>(acc6); acc7 = dpp_xor_add<0x4E>(acc7);
    // lane (ks) needs row m=ks; partner (ks^4) holds the other quad's partial
    const int k3 = ks & 3;
    float slo = (k3==0)?acc0:(k3==1)?acc1:(k3==2)?acc2:acc3;
    float shi = (k3==0)?acc4:(k3==1)?acc5:(k3==2)?acc6:acc7;
    float own  = (ks<4)? slo : shi;
    float give = (ks<4)? shi : slo;
    float tot = own + __shfl_xor(give, 4);
    float hnew = fmaxf(xpv + tot, 0.f);
    xo[jfin] = hnew;                                // overwrite xp slot with output
    h_last = hnew;
    *((f16*)(lds + LDSW + ((cur^1)<<10) + hwoff)) = (f16)hnew;
    // LDS-only barrier: no vmcnt drain needed (no cross-iteration global aliasing)
    asm volatile("s_waitcnt lgkmcnt(0)" ::: "memory");
    __builtin_amdgcn_s_barrier();
    cur ^= 1;
  }
  hn[jfin] = h_last;
}

// ---------------------------------------------------------------------------
extern "C" void kernel_launch(void* const* d_in, const int* in_sizes, int n_in,
                              void* d_out, int out_size, void* d_ws, size_t ws_size,
                              hipStream_t stream){
  const float* x    = (const float*)d_in[0];
  const float* h0   = (const float*)d_in[1];
  const float* wihf = (const float*)d_in[2];
  const float* whhf = (const float*)d_in[3];
  const float* bihf = (const float*)d_in[4];
  const float* bhhf = (const float*)d_in[5];
  const float* wihb = (const float*)d_in[6];
  const float* whhb = (const float*)d_in[7];
  const float* bihb = (const float*)d_in[8];
  const float* bhhb = (const float*)d_in[9];
  float* out = (float*)d_out;
  f16* wf16 = (f16*)d_ws;   // 1 MB

  cvt_w_kernel<<<256, 256, 0, stream>>>(whhf, whhb, wf16);
  proj_kernel<<<dim3(128, 16), 256, 0, stream>>>(x, wihf, wihb, bihf, bhhf, bihb, bhhb, out);
  (void)hipFuncSetAttribute((const void*)rnn_kernel,
                            hipFuncAttributeMaxDynamicSharedMemorySize, LDS_TOTAL);
  rnn_kernel<<<64, 512, LDS_TOTAL, stream>>>(wf16, h0, out);
}

// Round 2
// 660.685 us; speedup vs baseline: 1.1987x; 1.1987x over previous
//
#include <hip/hip_runtime.h>
#include <stdint.h>

#define B_ 32
#define S_ 512
#define I_ 256
#define H_ 512
#define OUTW 1024
#define OUTS_ELEMS (B_*S_*OUTW)   // 16777216

typedef _Float16 f16;
typedef _Float16 half2_t __attribute__((ext_vector_type(2)));

__device__ __forceinline__ float fdot2(uint32_t a, uint32_t b, float c){
#if __has_builtin(__builtin_amdgcn_fdot2)
  return __builtin_amdgcn_fdot2(__builtin_bit_cast(half2_t, a),
                                __builtin_bit_cast(half2_t, b), c, false);
#else
  half2_t ha = __builtin_bit_cast(half2_t, a);
  half2_t hb = __builtin_bit_cast(half2_t, b);
  return c + (float)ha.x*(float)hb.x + (float)ha.y*(float)hb.y;
#endif
}

__device__ __forceinline__ uint32_t packf16(float x, float y){
  union { f16 h[2]; uint32_t u; } z;
  z.h[0] = (f16)x; z.h[1] = (f16)y;
  return z.u;
}

template<int CTRL>
__device__ __forceinline__ float dpp_xor_add(float x){
  int v = __builtin_amdgcn_update_dpp(0, __float_as_int(x), CTRL, 0xF, 0xF, true);
  return x + __int_as_float(v);
}

// 16B-chunk XOR swizzle for the LDS h buffer (conflict-free b128 reads)
__device__ __forceinline__ int swz16(int chunk){  // chunk in 0..63
  return (chunk & ~7) | ((chunk ^ (chunk >> 3)) & 7);
}

// ---------------------------------------------------------------------------
// P0: convert W_hh (both dirs) fp32 -> f16 into d_ws:  wf16[2][512][512]
// ---------------------------------------------------------------------------
__global__ __launch_bounds__(256) void cvt_w_kernel(const float* __restrict__ wf,
                                                    const float* __restrict__ wb,
                                                    f16* __restrict__ out){
  int i = blockIdx.x*256 + threadIdx.x;        // 0..65535, 8 elems each
  const float* src = (i < 32768) ? wf : wb;
  int base = (i & 32767) * 8;
  float4 a = *(const float4*)(src + base);
  float4 c = *(const float4*)(src + base + 4);
  uint4 o;
  o.x = packf16(a.x, a.y); o.y = packf16(a.z, a.w);
  o.z = packf16(c.x, c.y); o.w = packf16(c.z, c.w);
  *(uint4*)(out + (size_t)i*8) = o;
}

// ---------------------------------------------------------------------------
// P1: xp staged into d_out (each cell read once by rnn, then overwritten).
// ---------------------------------------------------------------------------
#define PTM 128
#define PTN 64
#define PTK 32
__global__ __launch_bounds__(256) void proj_kernel(
    const float* __restrict__ x,
    const float* __restrict__ wihf, const float* __restrict__ wihb,
    const float* __restrict__ bihf, const float* __restrict__ bhhf,
    const float* __restrict__ bihb, const float* __restrict__ bhhb,
    float* __restrict__ out)
{
  __shared__ float As[PTK][132];
  __shared__ float Bs[PTK][68];
  const int tid = threadIdx.x;
  const int row0 = blockIdx.x * PTM;
  const int j0   = blockIdx.y * PTN;
  const int dir  = (j0 >= 512) ? 1 : 0;
  const int jl0  = j0 - dir*512;
  const float* wih = dir ? wihb : wihf;
  const float* bi  = dir ? bihb : bihf;
  const float* bh  = dir ? bhhb : bhhf;

  const int ty = tid >> 4, tx = tid & 15;
  float acc[8][4];
#pragma unroll
  for (int i=0;i<8;i++)
#pragma unroll
    for (int j=0;j<4;j++) acc[i][j] = 0.f;

  float bias[4];
#pragma unroll
  for (int jj=0;jj<4;jj++){ int jl = jl0 + tx*4 + jj; bias[jj] = bi[jl] + bh[jl]; }

  for (int k0 = 0; k0 < I_; k0 += PTK){
    {
      int r = tid >> 1, kh = (tid & 1) * 16;
      int rg = row0 + r; int bb = rg & 31, tt = rg >> 5;
      const float* ap = x + ((size_t)bb*S_ + tt)*I_ + k0 + kh;
#pragma unroll
      for (int u=0;u<4;u++){
        float4 v = *(const float4*)(ap + u*4);
        As[kh+u*4+0][r] = v.x; As[kh+u*4+1][r] = v.y;
        As[kh+u*4+2][r] = v.z; As[kh+u*4+3][r] = v.w;
      }
    }
    {
      int jr = tid >> 2, kh = (tid & 3) * 8;
      const float* bp = wih + (size_t)(jl0 + jr)*I_ + k0 + kh;
#pragma unroll
      for (int u=0;u<2;u++){
        float4 v = *(const float4*)(bp + u*4);
        Bs[kh+u*4+0][jr] = v.x; Bs[kh+u*4+1][jr] = v.y;
        Bs[kh+u*4+2][jr] = v.z; Bs[kh+u*4+3][jr] = v.w;
      }
    }
    __syncthreads();
#pragma unroll 8
    for (int kk=0; kk<PTK; ++kk){
      const float4 a0 = *(const float4*)&As[kk][ty*8+0];
      const float4 a1 = *(const float4*)&As[kk][ty*8+4];
      const float4 bq = *(const float4*)&Bs[kk][tx*4];
      const float av[8] = {a0.x,a0.y,a0.z,a0.w,a1.x,a1.y,a1.z,a1.w};
      const float bv[4] = {bq.x,bq.y,bq.z,bq.w};
#pragma unroll
      for (int i=0;i<8;i++)
#pragma unroll
        for (int j=0;j<4;j++) acc[i][j] = fmaf(av[i], bv[j], acc[i][j]);
    }
    __syncthreads();
  }
#pragma unroll
  for (int i=0;i<8;i++){
    int rg = row0 + ty*8 + i; int bb = rg & 31, tt = rg >> 5;
    float* op = out + ((size_t)bb*S_ + tt)*OUTW + j0 + tx*4;
    float4 v = {acc[i][0]+bias[0], acc[i][1]+bias[1], acc[i][2]+bias[2], acc[i][3]+bias[3]};
    *(float4*)op = v;
  }
}

// ---------------------------------------------------------------------------
// R: pair-split recurrence. 128 WGs: g -> dir=g>>6, b=(g>>1)&31, half=g&1.
// WG owns output rows [half*256, half*256+256); W-half lives ENTIRELY in
// 128 VGPRs/lane (wL+wR). Lane (jg=tid>>3, ks=tid&7) holds rows
// jl = jg + 64*m (m=0..3), k-slices: local  k = half*256  + ks*32 + [0,32)
//                                    remote k = half'*256 + ks*32 + [0,32).
// Per step: local fdot2 first (hides exchange), tagged-mailbox spin for the
// partner's 256 h (u32 = f16h<<16 | step-tag, relaxed agent atomics), stage
// into XOR-swizzled LDS h buffer, remote fdot2, DPP+shfl reduce, relu.
// ---------------------------------------------------------------------------
#define MAIL_OFF_U32 (1u<<18)   // d_ws: W f16 occupies 1 MB = 2^20 B = 2^18 u32

__global__ __launch_bounds__(512, 2) void rnn_kernel(
    const f16* __restrict__ Wall,   // [2][512][512] f16
    const float* __restrict__ h0,   // [2][32][512]
    float* dout, uint32_t* mailbase)
{
  __shared__ char lds[2048];       // 2 parity x 512 f16 (swizzled)
  const int tid  = threadIdx.x;
  const int g    = blockIdx.x;
  const int dir  = g >> 6;
  const int b    = (g >> 1) & 31;
  const int half = g & 1;
  const int jg   = tid >> 3;
  const int ks   = tid & 7;
  const int k3   = ks & 3;
  const bool owner = (ks < 4);
  const int jl   = jg + 64*k3;            // local row this lane finalizes (if owner)

  const f16* Wd = Wall + (size_t)dir * (H_*(size_t)H_);
  float* outs = dout + (size_t)b * (S_*OUTW);
  const int col = dir*512 + half*256 + jl;
  float* hn = dout + (size_t)OUTS_ELEMS + ((size_t)dir*B_ + b) * H_;

  uint32_t* mail = mailbase;              // [64 pairs][2 half][2 parity][256]
  const int pairid = dir*32 + b;
  uint32_t* mw = mail + ((size_t)pairid*2 + half) * 512;
  uint32_t* mr = mail + ((size_t)pairid*2 + (half^1)) * 512;

  // ---- W-half into registers: 4 rows x (32 local + 32 remote) f16 = 128 u32
  uint32_t wL[4][16], wR[4][16];
#pragma unroll
  for (int r=0;r<4;r++){
    const f16* row = Wd + (size_t)(half*256 + jg + 64*r) * H_;
    const uint4* pL = (const uint4*)(row + half*256 + ks*32);
    const uint4* pR = (const uint4*)(row + (half^1)*256 + ks*32);
#pragma unroll
    for (int q=0;q<4;q++){
      uint4 v = pL[q];
      wL[r][q*4+0]=v.x; wL[r][q*4+1]=v.y; wL[r][q*4+2]=v.z; wL[r][q*4+3]=v.w;
      uint4 u = pR[q];
      wR[r][q*4+0]=u.x; wR[r][q*4+1]=u.y; wR[r][q*4+2]=u.z; wR[r][q*4+3]=u.w;
    }
  }

  // ---- precomputed swizzled LDS byte offsets
  int oL[4], oR[4];
#pragma unroll
  for (int q=0;q<4;q++){
    oL[q] = swz16(half*32     + ks*4 + q) * 16;
    oR[q] = swz16((half^1)*32 + ks*4 + q) * 16;
  }
  const int kO = half*256 + jl;                    // owner's h slot (global k idx)
  const int oO = swz16(kO>>3)*16 + (kO&7)*2;
  const int kS = (half^1)*256 + tid;               // remote-stage slot (tid<256)
  const int oS = swz16(kS>>3)*16 + (kS&7)*2;

  // ---- prologue: stage full h0 into parity-1 buffer
  {
    int k = tid;
    int off = swz16(k>>3)*16 + (k&7)*2;
    *(f16*)(lds + 1024 + off) = (f16)h0[((size_t)dir*B_ + b)*H_ + k];
  }
  __syncthreads();

  for (int s=0; s<S_; ++s){
    const int t = dir ? (S_-1-s) : s;
    const int P = (s+1)&1;                          // == (s-1)&1
    char* hb = lds + P*1024;
    float* xo = outs + (size_t)t*OUTW;
    float xpv = 0.f;
    if (owner) xpv = xo[col];                       // issued early, used late

    float a0=0.f, a1=0.f, a2=0.f, a3=0.f;
    // ---- local half of the dot products (no dependence on partner)
#pragma unroll
    for (int q=0;q<4;q++){
      const uint4 hv = *(const uint4*)(hb + oL[q]);
      a0 = fdot2(wL[0][q*4+0],hv.x,a0); a0 = fdot2(wL[0][q*4+1],hv.y,a0);
      a0 = fdot2(wL[0][q*4+2],hv.z,a0); a0 = fdot2(wL[0][q*4+3],hv.w,a0);
      a1 = fdot2(wL[1][q*4+0],hv.x,a1); a1 = fdot2(wL[1][q*4+1],hv.y,a1);
      a1 = fdot2(wL[1][q*4+2],hv.z,a1); a1 = fdot2(wL[1][q*4+3],hv.w,a1);
      a2 = fdot2(wL[2][q*4+0],hv.x,a2); a2 = fdot2(wL[2][q*4+1],hv.y,a2);
      a2 = fdot2(wL[2][q*4+2],hv.z,a2); a2 = fdot2(wL[2][q*4+3],hv.w,a2);
      a3 = fdot2(wL[3][q*4+0],hv.x,a3); a3 = fdot2(wL[3][q*4+1],hv.y,a3);
      a3 = fdot2(wL[3][q*4+2],hv.z,a3); a3 = fdot2(wL[3][q*4+3],hv.w,a3);
    }
    // ---- receive partner's h_{s-1}: spin on tagged dwords, stage into LDS
    if (s > 0 && tid < 256){
      const uint32_t tag = (uint32_t)s & 0xffffu;
      uint32_t v;
      do {
        v = __hip_atomic_load(&mr[P*256 + tid], __ATOMIC_RELAXED, __HIP_MEMORY_SCOPE_AGENT);
      } while ((v & 0xffffu) != tag);
      uint16_t hb16 = (uint16_t)(v >> 16);
      *(f16*)(hb + oS) = __builtin_bit_cast(f16, hb16);
    }
    __syncthreads();
    // ---- remote half of the dot products
#pragma unroll
    for (int q=0;q<4;q++){
      const uint4 hv = *(const uint4*)(hb + oR[q]);
      a0 = fdot2(wR[0][q*4+0],hv.x,a0); a0 = fdot2(wR[0][q*4+1],hv.y,a0);
      a0 = fdot2(wR[0][q*4+2],hv.z,a0); a0 = fdot2(wR[0][q*4+3],hv.w,a0);
      a1 = fdot2(wR[1][q*4+0],hv.x,a1); a1 = fdot2(wR[1][q*4+1],hv.y,a1);
      a1 = fdot2(wR[1][q*4+2],hv.z,a1); a1 = fdot2(wR[1][q*4+3],hv.w,a1);
      a2 = fdot2(wR[2][q*4+0],hv.x,a2); a2 = fdot2(wR[2][q*4+1],hv.y,a2);
      a2 = fdot2(wR[2][q*4+2],hv.z,a2); a2 = fdot2(wR[2][q*4+3],hv.w,a2);
      a3 = fdot2(wR[3][q*4+0],hv.x,a3); a3 = fdot2(wR[3][q*4+1],hv.y,a3);
      a3 = fdot2(wR[3][q*4+2],hv.z,a3); a3 = fdot2(wR[3][q*4+3],hv.w,a3);
    }
    // ---- reduce over the 8 ks-lanes: quad DPP xor1+xor2, then shfl_xor(4)
    a0 = dpp_xor_add<0xB1>(a0); a1 = dpp_xor_add<0xB1>(a1);
    a2 = dpp_xor_add<0xB1>(a2); a3 = dpp_xor_add<0xB1>(a3);
    a0 = dpp_xor_add<0x4E>(a0); a1 = dpp_xor_add<0x4E>(a1);
    a2 = dpp_xor_add<0x4E>(a2); a3 = dpp_xor_add<0x4E>(a3);
    float own = (k3==0)?a0:(k3==1)?a1:(k3==2)?a2:a3;
    float tot = own + __shfl_xor(own, 4);

    if (owner){
      float h = fmaxf(xpv + tot, 0.f);
      xo[col] = h;                                   // overwrite xp slot
      if (s == S_-1) hn[half*256 + jl] = h;
      uint16_t hb16 = __builtin_bit_cast(uint16_t, (f16)h);
      *(f16*)(lds + (P^1)*1024 + oO) = __builtin_bit_cast(f16, hb16);
      uint32_t val = ((uint32_t)hb16 << 16) | ((uint32_t)(s+1) & 0xffffu);
      __hip_atomic_store(&mw[(P^1)*256 + jl], val, __ATOMIC_RELAXED, __HIP_MEMORY_SCOPE_AGENT);
    }
    __syncthreads();
  }
}

// ---------------------------------------------------------------------------
extern "C" void kernel_launch(void* const* d_in, const int* in_sizes, int n_in,
                              void* d_out, int out_size, void* d_ws, size_t ws_size,
                              hipStream_t stream){
  const float* x    = (const float*)d_in[0];
  const float* h0   = (const float*)d_in[1];
  const float* wihf = (const float*)d_in[2];
  const float* whhf = (const float*)d_in[3];
  const float* bihf = (const float*)d_in[4];
  const float* bhhf = (const float*)d_in[5];
  const float* wihb = (const float*)d_in[6];
  const float* whhb = (const float*)d_in[7];
  const float* bihb = (const float*)d_in[8];
  const float* bhhb = (const float*)d_in[9];
  float* out = (float*)d_out;
  f16* wf16 = (f16*)d_ws;                       // 1 MB
  uint32_t* mail = (uint32_t*)d_ws + MAIL_OFF_U32;  // 256 KB mailbox

  cvt_w_kernel<<<256, 256, 0, stream>>>(whhf, whhb, wf16);
  proj_kernel<<<dim3(128, 16), 256, 0, stream>>>(x, wihf, wihb, bihf, bhhf, bihb, bhhb, out);
  rnn_kernel<<<128, 512, 0, stream>>>(wf16, h0, out, mail);
}